// Round 11
// baseline (166.978 us; speedup 1.0000x reference)
//
#include <hip/hip_runtime.h>

// GCN forward on MI355X:
//   out = log_softmax(adj @ (relu(adj @ (x@W1) + b1) @ W2) + b2)
// N=8192, NFEAT=512, NHID=128, NCLASS=40. adj is 256MB f32, SYMMETRIC.
// Round 11 = round 10 with ONE subsystem changed: k2 -> k2a (BM=64 rows,
// split-K=2, grid 128x2, 33% fewer VMEM instructions per adj byte, half the
// Stf L2 traffic) + k2b (add halves + bias + relu -> H). k4 unchanged as
// control. Theory: VMEM address-rate (TA) is co-saturated with HBM.
//   k0   W1 -> W1f  (bf16 B-fragment-linear)
//   k1   support = x@W1 -> Stf (B-fragment-linear, barrier-free)
//   k2a  Hpart[kh] = S^T@adj(k-half)  [fwd stream, BM=64]
//   k2b  H = relu(Hpart[0]+Hpart[1]+b1)  bf16 [8192][128]
//   k3   s2 = h@W2 -> S2f (B-fragment-linear, 64 cols, 40..63 zero)
//   k4   logits^T = s2^T@adj (+bias) -> log_softmax -> OUT  [bwd stream]
// Fragment conventions (validated rounds 1-10):
//   A-frag (ct,kb): lane l, j -> A[ct*16+(l&15)][kb*32+(l>>4)*8+j]
//   B-frag via adj symmetry: lane l, j -> adj[row=g*16+(l&15)][k]
//   C/D: N-col = ct*16+(lane&15), M-row = mt*16+(lane>>4)*4+i

using bf16x8 = __attribute__((ext_vector_type(8))) __bf16;
using f32x4  = __attribute__((ext_vector_type(4))) float;
using u16x4  = __attribute__((ext_vector_type(4))) unsigned short;
using u16x8  = __attribute__((ext_vector_type(8))) unsigned short;

#define NROW 8192
#define KFEAT 512
#define HID 128
#define NCLS 40

__device__ __forceinline__ unsigned short f2b(float f) {
  union { float f; unsigned u; } v; v.f = f;
  unsigned r = v.u + 0x7fffu + ((v.u >> 16) & 1u);
  return (unsigned short)(r >> 16);
}

__device__ __forceinline__ bf16x8 ldb8(const unsigned short* p) {
  return *reinterpret_cast<const bf16x8*>(p);
}

// K0: W1f B-fragment-linear from W1[512][128]
__global__ __launch_bounds__(256) void k0_w1f(const float* __restrict__ W1,
                                              unsigned short* __restrict__ W1f)
{
  int id = blockIdx.x * 256 + threadIdx.x;   // 0..8191
  int l16 = id & 63, blkid = id >> 6;
  int kb = blkid & 15, ct = blkid >> 4;
  int c = ct * 16 + (l16 & 15);
  int k0 = kb * 32 + (l16 >> 4) * 8;
  u16x8 pk;
#pragma unroll
  for (int j = 0; j < 8; ++j) pk[j] = f2b(W1[(size_t)(k0 + j) * HID + c]);
  *reinterpret_cast<u16x8*>(W1f + (size_t)id * 8) = pk;
}

// K1: support = x @ W1 -> Stf B-frag-linear. Barrier-free (rounds 7-10).
#define K1STEP(IT, A0, A1, B0, B1)                                             \
  {                                                                            \
    f32x4 na0, na1; bf16x8 nb0, nb1;                                           \
    if ((IT) + 2 < 16) {                                                       \
      na0 = *reinterpret_cast<const f32x4*>(ap + ((IT) + 2) * 32);             \
      na1 = *reinterpret_cast<const f32x4*>(ap + ((IT) + 2) * 32 + 4);         \
      nb0 = ldb8(bp0 + ((IT) + 2) * 512);                                      \
      nb1 = ldb8(bp1 + ((IT) + 2) * 512);                                      \
    }                                                                          \
    u16x8 tp;                                                                  \
    _Pragma("unroll")                                                          \
    for (int j = 0; j < 4; ++j) { tp[j] = f2b(A0[j]); tp[j + 4] = f2b(A1[j]); }\
    bf16x8 af = __builtin_bit_cast(bf16x8, tp);                                \
    acc[0] = __builtin_amdgcn_mfma_f32_16x16x32_bf16(af, B0, acc[0], 0, 0, 0); \
    acc[1] = __builtin_amdgcn_mfma_f32_16x16x32_bf16(af, B1, acc[1], 0, 0, 0); \
    if ((IT) + 2 < 16) { A0 = na0; A1 = na1; B0 = nb0; B1 = nb1; }             \
  }

__global__ __launch_bounds__(256) void k1_support(const float* __restrict__ X,
                                                  const unsigned short* __restrict__ W1f,
                                                  unsigned short* __restrict__ Stf)
{
  const int tid = threadIdx.x;
  const int lane = tid & 63, w = tid >> 6;
  const int l15 = lane & 15, lg = lane >> 4;
  const int blk = blockIdx.x, m0 = blk * 16;
  const float* ap = X + (size_t)(m0 + l15) * KFEAT + lg * 8;
  const unsigned short* bp0 = W1f + (size_t)((2 * w) * 16) * 512 + lane * 8;
  const unsigned short* bp1 = W1f + (size_t)((2 * w + 1) * 16) * 512 + lane * 8;
  f32x4 acc[2] = {};
  f32x4 aX0, aX1, aY0, aY1;
  bf16x8 bX0, bX1, bY0, bY1;
  aX0 = *reinterpret_cast<const f32x4*>(ap);
  aX1 = *reinterpret_cast<const f32x4*>(ap + 4);
  aY0 = *reinterpret_cast<const f32x4*>(ap + 32);
  aY1 = *reinterpret_cast<const f32x4*>(ap + 36);
  bX0 = ldb8(bp0); bX1 = ldb8(bp1);
  bY0 = ldb8(bp0 + 512); bY1 = ldb8(bp1 + 512);
  for (int it = 0; it < 16; it += 2) {
    K1STEP(it,     aX0, aX1, bX0, bX1);
    K1STEP(it + 1, aY0, aY1, bY0, bY1);
  }
  const int kb  = blk >> 1;
  const int lgc = ((blk & 1) << 1) + (lg >> 1);
  const int jb  = (lg & 1) * 4;
#pragma unroll
  for (int c = 0; c < 2; ++c) {
    int ctc = w * 2 + c;
    u16x4 pk;
#pragma unroll
    for (int i = 0; i < 4; ++i) pk[i] = f2b(acc[c][i]);
    *reinterpret_cast<u16x4*>(Stf + (size_t)(ctc * 256 + kb) * 512 +
                              (l15 + 16 * lgc) * 8 + jb) = pk;
  }
}

// ---- K2a: Hpart[kh] = S^T @ adj (k-half), BM=64 rows, forward stream ----
// Grid 256 = 128 row-tiles x 2 k-halves, 512 thr. Wave (mtg = w>>2, kg = w&3):
// hid tiles mtg*64..+63, K-panel kh*4096 + kg*1024 (32 iters of 32-k).
// Per iter: 8 adj B-loads (4 row-groups x 2) + 4 Stf A-loads, 16 MFMA.
#define K2STEP(IT, AS, BS)                                                     \
  {                                                                            \
    u16x8 tq[4];                                                               \
    _Pragma("unroll")                                                          \
    for (int g = 0; g < 4; ++g)                                                \
      _Pragma("unroll")                                                        \
      for (int j = 0; j < 4; ++j) {                                            \
        tq[g][j] = f2b(BS[g][0][j]); tq[g][j + 4] = f2b(BS[g][1][j]);          \
      }                                                                        \
    _Pragma("unroll")                                                          \
    for (int mt = 0; mt < 4; ++mt)                                             \
      _Pragma("unroll")                                                        \
      for (int g = 0; g < 4; ++g)                                              \
        acc[mt][g] = __builtin_amdgcn_mfma_f32_16x16x32_bf16(                  \
            AS[mt], __builtin_bit_cast(bf16x8, tq[g]), acc[mt][g], 0, 0, 0);   \
    if ((IT) + 2 < 32) {                                                       \
      _Pragma("unroll")                                                        \
      for (int mt = 0; mt < 4; ++mt)                                           \
        AS[mt] = ldb8(apt + ((size_t)((mtg * 4 + mt) * 256 + kb0 +             \
                                      (IT) + 2) << 9));                        \
      _Pragma("unroll")                                                        \
      for (int g = 0; g < 4; ++g) {                                            \
        BS[g][0] = *reinterpret_cast<const f32x4*>(bp[g] + ((IT) + 2) * 32);   \
        BS[g][1] = *reinterpret_cast<const f32x4*>(bp[g] + ((IT) + 2) * 32 + 4);\
      }                                                                        \
    }                                                                          \
  }

__global__ __launch_bounds__(512, 2) void k2a(const float* __restrict__ ADJ,
                                              const unsigned short* __restrict__ Stf,
                                              float* __restrict__ Hpart)
{
  __shared__ float Ls[8 * 2112];   // 66KB, row-stride 33 (bank-spread)
  const int tid = threadIdx.x;
  const int lane = tid & 63, w = tid >> 6;
  const int l15 = lane & 15, lg = lane >> 4;
  const int rt = blockIdx.x >> 1, kh = blockIdx.x & 1;
  const int n0 = rt * 64;
  const int mtg = w >> 2, kg = w & 3;
  const int kb0 = kh * 128 + kg * 32;

  const float* bp[4];
#pragma unroll
  for (int g = 0; g < 4; ++g)
    bp[g] = ADJ + (size_t)(n0 + g * 16 + l15) * NROW + kb0 * 32 + lg * 8;
  const unsigned short* apt = Stf + lane * 8;

  f32x4 acc[4][4];
#pragma unroll
  for (int mt = 0; mt < 4; ++mt)
#pragma unroll
    for (int g = 0; g < 4; ++g) acc[mt][g] = f32x4{};

  bf16x8 aX[4], aY[4];
  f32x4 bX[4][2], bY[4][2];
#pragma unroll
  for (int mt = 0; mt < 4; ++mt)
    aX[mt] = ldb8(apt + ((size_t)((mtg * 4 + mt) * 256 + kb0) << 9));
#pragma unroll
  for (int g = 0; g < 4; ++g) {
    bX[g][0] = *reinterpret_cast<const f32x4*>(bp[g]);
    bX[g][1] = *reinterpret_cast<const f32x4*>(bp[g] + 4);
  }
#pragma unroll
  for (int mt = 0; mt < 4; ++mt)
    aY[mt] = ldb8(apt + ((size_t)((mtg * 4 + mt) * 256 + kb0 + 1) << 9));
#pragma unroll
  for (int g = 0; g < 4; ++g) {
    bY[g][0] = *reinterpret_cast<const f32x4*>(bp[g] + 32);
    bY[g][1] = *reinterpret_cast<const f32x4*>(bp[g] + 36);
  }

  for (int it = 0; it < 32; it += 2) {
    K2STEP(it,     aX, bX);
    K2STEP(it + 1, aY, bY);
  }

  // Epilogue: reduce 4 kg-slabs per mtg, two row-phases (rows 0-31, 32-63).
  // Slab layout [hid 0..63][row 0..31], row-stride 33 floats.
#pragma unroll
  for (int ph = 0; ph < 2; ++ph) {
#pragma unroll
    for (int mt = 0; mt < 4; ++mt)
#pragma unroll
      for (int gg = 0; gg < 2; ++gg)
#pragma unroll
        for (int i = 0; i < 4; ++i)
          Ls[(mtg * 4 + kg) * 2112 + (mt * 16 + lg * 4 + i) * 33 +
             gg * 16 + l15] = acc[mt][ph * 2 + gg][i];
    __syncthreads();
    {
      const int mtg_r = tid >> 8;         // 0..1
      const int idx2 = tid & 255;
      const int row = idx2 >> 3;          // 0..31
      const int hc = (idx2 & 7) * 8;      // hid chunk 0..56
      float s[8] = {0.f, 0.f, 0.f, 0.f, 0.f, 0.f, 0.f, 0.f};
#pragma unroll
      for (int sl = 0; sl < 4; ++sl)
#pragma unroll
        for (int j = 0; j < 8; ++j)
          s[j] += Ls[(mtg_r * 4 + sl) * 2112 + (hc + j) * 33 + row];
      float* dst = Hpart + ((size_t)kh * NROW + n0 + ph * 32 + row) * HID +
                   mtg_r * 64 + hc;
      f32x4 v0, v1;
#pragma unroll
      for (int j = 0; j < 4; ++j) { v0[j] = s[j]; v1[j] = s[j + 4]; }
      *reinterpret_cast<f32x4*>(dst) = v0;
      *reinterpret_cast<f32x4*>(dst + 4) = v1;
    }
    __syncthreads();
  }
}

// K2b: H = relu(Hpart[0] + Hpart[1] + b1), bf16 [8192][128]
__global__ __launch_bounds__(256) void k2b(const float* __restrict__ Hpart,
                                           const float* __restrict__ b1,
                                           unsigned short* __restrict__ H)
{
  const int i0 = (blockIdx.x * 256 + threadIdx.x) * 8;   // grid 512
  f32x4 a0 = *reinterpret_cast<const f32x4*>(Hpart + i0);
  f32x4 a1 = *reinterpret_cast<const f32x4*>(Hpart + i0 + 4);
  f32x4 c0 = *reinterpret_cast<const f32x4*>(Hpart + (size_t)NROW * HID + i0);
  f32x4 c1 = *reinterpret_cast<const f32x4*>(Hpart + (size_t)NROW * HID + i0 + 4);
  const int hid = i0 & 127;
  u16x8 pk;
#pragma unroll
  for (int j = 0; j < 4; ++j) {
    float v = a0[j] + c0[j] + b1[hid + j];
    pk[j] = f2b(v > 0.f ? v : 0.f);
    float u = a1[j] + c1[j] + b1[hid + 4 + j];
    pk[j + 4] = f2b(u > 0.f ? u : 0.f);
  }
  *reinterpret_cast<u16x8*>(H + i0) = pk;
}

// K3: s2 = h @ W2 -> S2f B-fragment-linear (rounds 5-10 verbatim)
__global__ __launch_bounds__(256) void k3_s2(const unsigned short* __restrict__ H,
                                             const float* __restrict__ W2,
                                             unsigned short* __restrict__ S2f)
{
  __shared__ unsigned short W2t[64 * 136];
  const int tid = threadIdx.x;
  {
    const int n = tid >> 2;
    const int ks = (tid & 3) * 32;
    for (int j = 0; j < 32; ++j) {
      int k = ks + j;
      float v = (n < NCLS) ? W2[k * NCLS + n] : 0.f;
      W2t[n * 136 + k] = f2b(v);
    }
  }
  __syncthreads();
  const int lane = tid & 63, wave = tid >> 6;
  const int l15 = lane & 15, lg = lane >> 4;
  const int blk = blockIdx.x;
  const int m0 = blk * 64;
  const int rowm = m0 + wave * 16 + l15;
  f32x4 acc[4] = {};
#pragma unroll
  for (int kk = 0; kk < 4; ++kk) {
    bf16x8 af = *reinterpret_cast<const bf16x8*>(H + (size_t)rowm * HID + kk * 32 + lg * 8);
#pragma unroll
    for (int n = 0; n < 4; ++n) {
      bf16x8 bf = *reinterpret_cast<const bf16x8*>(&W2t[(n * 16 + l15) * 136 + kk * 32 + lg * 8]);
      acc[n] = __builtin_amdgcn_mfma_f32_16x16x32_bf16(af, bf, acc[n], 0, 0, 0);
    }
  }
  const int kb  = blk * 2 + (wave >> 1);
  const int lgc = ((wave & 1) << 1) + (lg >> 1);
  const int jb  = (lg & 1) * 4;
#pragma unroll
  for (int n = 0; n < 4; ++n) {
    u16x4 pk;
#pragma unroll
    for (int i = 0; i < 4; ++i) pk[i] = f2b(acc[n][i]);
    *reinterpret_cast<u16x4*>(S2f + (size_t)(n * 256 + kb) * 512 +
                              (l15 + 16 * lgc) * 8 + jb) = pk;
  }
}

// ---- round-10 4-phase adj-stream (k4 only, BACKWARD) ----
#define KPH(BB, AS, T, P, DO_A, DO_B, SGN)                                     \
  {                                                                            \
    u16x8 t0_, t1_;                                                            \
    _Pragma("unroll")                                                          \
    for (int j = 0; j < 4; ++j) {                                              \
      t0_[j] = f2b(BB[0][j]); t0_[j + 4] = f2b(BB[1][j]);                      \
      t1_[j] = f2b(BB[2][j]); t1_[j + 4] = f2b(BB[3][j]);                      \
    }                                                                          \
    bf16x8 f0_ = __builtin_bit_cast(bf16x8, t0_);                              \
    bf16x8 f1_ = __builtin_bit_cast(bf16x8, t1_);                              \
    _Pragma("unroll")                                                          \
    for (int mt = 0; mt < MT_; ++mt) {                                         \
      acc[mt][0] = __builtin_amdgcn_mfma_f32_16x16x32_bf16(AS[mt], f0_,        \
                                                           acc[mt][0], 0,0,0); \
      acc[mt][1] = __builtin_amdgcn_mfma_f32_16x16x32_bf16(AS[mt], f1_,        \
                                                           acc[mt][1], 0,0,0); \
    }                                                                          \
    if (DO_A) {                                                                \
      _Pragma("unroll")                                                        \
      for (int mt = 0; mt < MT_; ++mt)                                         \
        AS[mt] = ldb8(apt + ((size_t)(mt * 256 + kbb +                         \
                                      (SGN) * ((T) + (P) + 2)) << 9));         \
    }                                                                          \
    if (DO_B) {                                                                \
      BB[0] = *reinterpret_cast<const f32x4*>(bpt0 + (SGN)*((T)+(P)+4)*32);    \
      BB[1] = *reinterpret_cast<const f32x4*>(bpt0 + (SGN)*((T)+(P)+4)*32 + 4);\
      BB[2] = *reinterpret_cast<const f32x4*>(bpt1 + (SGN)*((T)+(P)+4)*32);    \
      BB[3] = *reinterpret_cast<const f32x4*>(bpt1 + (SGN)*((T)+(P)+4)*32 + 4);\
    }                                                                          \
  }

#define KPROLOGUE(MT, SGN)                                                     \
  _Pragma("unroll")                                                            \
  for (int mt = 0; mt < (MT); ++mt)                                            \
    aS0[mt] = ldb8(apt + ((size_t)(mt * 256 + kbb) << 9));                     \
  bb0[0] = *reinterpret_cast<const f32x4*>(bpt0);                              \
  bb0[1] = *reinterpret_cast<const f32x4*>(bpt0 + 4);                          \
  bb0[2] = *reinterpret_cast<const f32x4*>(bpt1);                              \
  bb0[3] = *reinterpret_cast<const f32x4*>(bpt1 + 4);                          \
  _Pragma("unroll")                                                            \
  for (int mt = 0; mt < (MT); ++mt)                                            \
    aS1[mt] = ldb8(apt + ((size_t)(mt * 256 + kbb + (SGN)) << 9));             \
  bb1[0] = *reinterpret_cast<const f32x4*>(bpt0 + (SGN) * 32);                 \
  bb1[1] = *reinterpret_cast<const f32x4*>(bpt0 + (SGN) * 32 + 4);             \
  bb1[2] = *reinterpret_cast<const f32x4*>(bpt1 + (SGN) * 32);                 \
  bb1[3] = *reinterpret_cast<const f32x4*>(bpt1 + (SGN) * 32 + 4);             \
  bb2[0] = *reinterpret_cast<const f32x4*>(bpt0 + (SGN) * 64);                 \
  bb2[1] = *reinterpret_cast<const f32x4*>(bpt0 + (SGN) * 64 + 4);             \
  bb2[2] = *reinterpret_cast<const f32x4*>(bpt1 + (SGN) * 64);                 \
  bb2[3] = *reinterpret_cast<const f32x4*>(bpt1 + (SGN) * 64 + 4);             \
  bb3[0] = *reinterpret_cast<const f32x4*>(bpt0 + (SGN) * 96);                 \
  bb3[1] = *reinterpret_cast<const f32x4*>(bpt0 + (SGN) * 96 + 4);             \
  bb3[2] = *reinterpret_cast<const f32x4*>(bpt1 + (SGN) * 96);                 \
  bb3[3] = *reinterpret_cast<const f32x4*>(bpt1 + (SGN) * 96 + 4);

#define KMAIN(SGN)                                                             \
  for (int t = 0; t < 28; t += 4) {                                            \
    KPH(bb0, aS0, t, 0, 1, 1, SGN);                                            \
    KPH(bb1, aS1, t, 1, 1, 1, SGN);                                            \
    KPH(bb2, aS0, t, 2, 1, 1, SGN);                                            \
    KPH(bb3, aS1, t, 3, 1, 1, SGN);                                            \
  }                                                                            \
  KPH(bb0, aS0, 28, 0, 1, 0, SGN);                                             \
  KPH(bb1, aS1, 28, 1, 1, 0, SGN);                                             \
  KPH(bb2, aS0, 28, 2, 0, 0, SGN);                                             \
  KPH(bb3, aS1, 28, 3, 0, 0, SGN);

// K4: logits^T = s2^T @ adj (+b2) -> log_softmax -> OUT. BACKWARD stream.
__global__ __launch_bounds__(512, 2) void k4_out(const float* __restrict__ ADJ,
                                                 const unsigned short* __restrict__ S2f,
                                                 const float* __restrict__ b2,
                                                 float* __restrict__ OUT)
{
  __shared__ float Ls[4 * 2048];   // 32 KB: 4 merged slabs
  __shared__ float Lg[32 * 64];    // 8 KB logits [row][class]
  const int tid = threadIdx.x;
  const int lane = tid & 63, w = tid >> 6;
  const int l15 = lane & 15, lg = lane >> 4;
  const int n0 = blockIdx.x * 32;
  const int kbg0 = w * 32;
  const int kbb = kbg0 + 31;                // backward
  constexpr int MT_ = 4;

  const float* bpt0 = ADJ + (size_t)(n0 + l15) * NROW + kbb * 32 + lg * 8;
  const float* bpt1 = bpt0 + (size_t)16 * NROW;
  const unsigned short* apt = S2f + lane * 8;

  f32x4 acc[MT_][2];
#pragma unroll
  for (int m = 0; m < MT_; ++m) { acc[m][0] = f32x4{}; acc[m][1] = f32x4{}; }

  bf16x8 aS0[MT_], aS1[MT_];
  f32x4 bb0[4], bb1[4], bb2[4], bb3[4];
  KPROLOGUE(MT_, -1);
  KMAIN(-1);

  if (w >= 4) {
#pragma unroll
    for (int mt = 0; mt < MT_; ++mt)
#pragma unroll
      for (int c2 = 0; c2 < 2; ++c2)
#pragma unroll
        for (int i = 0; i < 4; ++i)
          Ls[(w - 4) * 2048 + (mt * 16 + lg * 4 + i) * 32 + c2 * 16 + l15] =
              acc[mt][c2][i];
  }
  __syncthreads();
  if (w < 4) {
#pragma unroll
    for (int mt = 0; mt < MT_; ++mt)
#pragma unroll
      for (int c2 = 0; c2 < 2; ++c2)
#pragma unroll
        for (int i = 0; i < 4; ++i) {
          const int idx = w * 2048 + (mt * 16 + lg * 4 + i) * 32 + c2 * 16 + l15;
          Ls[idx] += acc[mt][c2][i];
        }
  }
  __syncthreads();

  {
    const int e0 = tid * 4;
    f32x4 s = {};
#pragma unroll
    for (int ww = 0; ww < 4; ++ww)
      s += *reinterpret_cast<const f32x4*>(&Ls[ww * 2048 + e0]);
    const int c = e0 >> 5;
    const int nl0 = e0 & 31;
    const float bias = (c < NCLS) ? b2[c] : 0.f;
#pragma unroll
    for (int j = 0; j < 4; ++j)
      Lg[(nl0 + j) * 64 + c] = s[j] + bias;
  }
  __syncthreads();

  {
    const int row = tid >> 4;
    const int sub = tid & 15;
    float vals[3];
    int nc = 0;
    float mx = -3.4e38f;
    for (int c = sub; c < NCLS; c += 16) {
      float v = Lg[row * 64 + c];
      vals[nc++] = v;
      mx = fmaxf(mx, v);
    }
#pragma unroll
    for (int d = 1; d < 16; d <<= 1) mx = fmaxf(mx, __shfl_xor(mx, d));
    float se = 0.f;
    for (int j = 0; j < nc; ++j) se += expf(vals[j] - mx);
#pragma unroll
    for (int d = 1; d < 16; d <<= 1) se += __shfl_xor(se, d);
    const float lse = mx + logf(se);
    int j = 0;
    for (int c = sub; c < NCLS; c += 16)
      OUT[(size_t)(n0 + row) * NCLS + c] = vals[j++] - lse;
  }
}

extern "C" void kernel_launch(void* const* d_in, const int* in_sizes, int n_in,
                              void* d_out, int out_size, void* d_ws, size_t ws_size,
                              hipStream_t stream)
{
  const float* x   = (const float*)d_in[0];
  const float* adj = (const float*)d_in[1];
  const float* W1  = (const float*)d_in[2];
  const float* b1  = (const float*)d_in[3];
  const float* W2  = (const float*)d_in[4];
  const float* b2  = (const float*)d_in[5];
  float* out = (float*)d_out;

  char* ws = (char*)d_ws;
  unsigned short* W1f   = (unsigned short*)(ws);                        // 128KB
  unsigned short* Stf   = (unsigned short*)(ws + 131072);               // 2MB
  unsigned short* H     = (unsigned short*)(ws + 2228224);              // 2MB
  unsigned short* S2f   = (unsigned short*)(ws + 4325376);              // 1MB
  float*          Hpart = (float*)(ws + 5373952);                       // 8MB

  hipLaunchKernelGGL(k0_w1f,     dim3(32),  dim3(256), 0, stream, W1, W1f);
  hipLaunchKernelGGL(k1_support, dim3(512), dim3(256), 0, stream, x, W1f, Stf);
  hipLaunchKernelGGL(k2a,        dim3(256), dim3(512), 0, stream, adj, Stf, Hpart);
  hipLaunchKernelGGL(k2b,        dim3(512), dim3(256), 0, stream, Hpart, b1, H);
  hipLaunchKernelGGL(k3_s2,      dim3(128), dim3(256), 0, stream, H, W2, S2f);
  hipLaunchKernelGGL(k4_out,     dim3(256), dim3(512), 0, stream, adj, S2f, b2, out);
}

// Round 12
// 136.154 us; speedup vs baseline: 1.2264x; 1.2264x over previous
//
#include <hip/hip_runtime.h>

// GCN forward on MI355X:
//   out = log_softmax(adj @ (relu(adj @ (x@W1) + b1) @ W2) + b2)
// N=8192, NFEAT=512, NHID=128, NCLASS=40. adj is 256MB f32, SYMMETRIC.
// Round 12 = REVERT to round 9 (best measured, 136.4us). Round 11's BM=64
// split-K regressed (VGPR pressure + broke the fwd/bwd L3 alternation).
// Structure: adj symmetry -> adj as B operand, barrier-free register streams;
// k2 forward / k4 backward (boustrophedon) sustains ~50% L3 retention of the
// exactly-cache-sized adj across kernels and timed replays (FETCH 137/258MB).
//   k0   W1 -> W1f  (bf16 B-fragment-linear)
//   k1   support = x@W1 -> Stf (B-fragment-linear, barrier-free)
//   k2   h^T = S^T@adj (+bias,relu) -> H row-major bf16 [8192][128]  [fwd]
//   k3   s2 = h@W2 -> S2f (B-fragment-linear, 64 cols, 40..63 zero)
//   k4   logits^T = s2^T@adj (+bias) -> log_softmax -> OUT           [bwd]
// Fragment conventions (validated rounds 1-9):
//   A-frag (mt,kb): lane l, j -> A[mt*16+(l&15)][kb*32+(l>>4)*8+j]
//   B-frag (ct,kb): lane l, j -> B[kb*32+(l>>4)*8+j][ct*16+(l&15)]
//   C/D: N-col = ct*16+(lane&15), M-row = mt*16+(lane>>4)*4+i

using bf16x8 = __attribute__((ext_vector_type(8))) __bf16;
using f32x4  = __attribute__((ext_vector_type(4))) float;
using u16x4  = __attribute__((ext_vector_type(4))) unsigned short;
using u16x8  = __attribute__((ext_vector_type(8))) unsigned short;

#define NROW 8192
#define KFEAT 512
#define HID 128
#define NCLS 40

__device__ __forceinline__ unsigned short f2b(float f) {
  union { float f; unsigned u; } v; v.f = f;
  unsigned r = v.u + 0x7fffu + ((v.u >> 16) & 1u);
  return (unsigned short)(r >> 16);
}

__device__ __forceinline__ bf16x8 ldb8(const unsigned short* p) {
  return *reinterpret_cast<const bf16x8*>(p);
}

// K0: W1f B-fragment-linear from W1[512][128]
__global__ __launch_bounds__(256) void k0_w1f(const float* __restrict__ W1,
                                              unsigned short* __restrict__ W1f)
{
  int id = blockIdx.x * 256 + threadIdx.x;   // 0..8191
  int l16 = id & 63, blkid = id >> 6;
  int kb = blkid & 15, ct = blkid >> 4;
  int c = ct * 16 + (l16 & 15);
  int k0 = kb * 32 + (l16 >> 4) * 8;
  u16x8 pk;
#pragma unroll
  for (int j = 0; j < 8; ++j) pk[j] = f2b(W1[(size_t)(k0 + j) * HID + c]);
  *reinterpret_cast<u16x8*>(W1f + (size_t)id * 8) = pk;
}

// K1: support = x @ W1 -> Stf B-frag-linear. Barrier-free (rounds 7-9).
#define K1STEP(IT, A0, A1, B0, B1)                                             \
  {                                                                            \
    f32x4 na0, na1; bf16x8 nb0, nb1;                                           \
    if ((IT) + 2 < 16) {                                                       \
      na0 = *reinterpret_cast<const f32x4*>(ap + ((IT) + 2) * 32);             \
      na1 = *reinterpret_cast<const f32x4*>(ap + ((IT) + 2) * 32 + 4);         \
      nb0 = ldb8(bp0 + ((IT) + 2) * 512);                                      \
      nb1 = ldb8(bp1 + ((IT) + 2) * 512);                                      \
    }                                                                          \
    u16x8 tp;                                                                  \
    _Pragma("unroll")                                                          \
    for (int j = 0; j < 4; ++j) { tp[j] = f2b(A0[j]); tp[j + 4] = f2b(A1[j]); }\
    bf16x8 af = __builtin_bit_cast(bf16x8, tp);                                \
    acc[0] = __builtin_amdgcn_mfma_f32_16x16x32_bf16(af, B0, acc[0], 0, 0, 0); \
    acc[1] = __builtin_amdgcn_mfma_f32_16x16x32_bf16(af, B1, acc[1], 0, 0, 0); \
    if ((IT) + 2 < 16) { A0 = na0; A1 = na1; B0 = nb0; B1 = nb1; }             \
  }

__global__ __launch_bounds__(256) void k1_support(const float* __restrict__ X,
                                                  const unsigned short* __restrict__ W1f,
                                                  unsigned short* __restrict__ Stf)
{
  const int tid = threadIdx.x;
  const int lane = tid & 63, w = tid >> 6;
  const int l15 = lane & 15, lg = lane >> 4;
  const int blk = blockIdx.x, m0 = blk * 16;
  const float* ap = X + (size_t)(m0 + l15) * KFEAT + lg * 8;
  const unsigned short* bp0 = W1f + (size_t)((2 * w) * 16) * 512 + lane * 8;
  const unsigned short* bp1 = W1f + (size_t)((2 * w + 1) * 16) * 512 + lane * 8;
  f32x4 acc[2] = {};
  f32x4 aX0, aX1, aY0, aY1;
  bf16x8 bX0, bX1, bY0, bY1;
  aX0 = *reinterpret_cast<const f32x4*>(ap);
  aX1 = *reinterpret_cast<const f32x4*>(ap + 4);
  aY0 = *reinterpret_cast<const f32x4*>(ap + 32);
  aY1 = *reinterpret_cast<const f32x4*>(ap + 36);
  bX0 = ldb8(bp0); bX1 = ldb8(bp1);
  bY0 = ldb8(bp0 + 512); bY1 = ldb8(bp1 + 512);
  for (int it = 0; it < 16; it += 2) {
    K1STEP(it,     aX0, aX1, bX0, bX1);
    K1STEP(it + 1, aY0, aY1, bY0, bY1);
  }
  const int kb  = blk >> 1;
  const int lgc = ((blk & 1) << 1) + (lg >> 1);
  const int jb  = (lg & 1) * 4;
#pragma unroll
  for (int c = 0; c < 2; ++c) {
    int ctc = w * 2 + c;
    u16x4 pk;
#pragma unroll
    for (int i = 0; i < 4; ++i) pk[i] = f2b(acc[c][i]);
    *reinterpret_cast<u16x4*>(Stf + (size_t)(ctc * 256 + kb) * 512 +
                              (l15 + 16 * lgc) * 8 + jb) = pk;
  }
}

// ---- 4-phase adj-stream body, direction-parameterized (round 9 verbatim) ----
#define KPH(BB, AS, T, P, DO_A, DO_B, SGN)                                     \
  {                                                                            \
    u16x8 t0_, t1_;                                                            \
    _Pragma("unroll")                                                          \
    for (int j = 0; j < 4; ++j) {                                              \
      t0_[j] = f2b(BB[0][j]); t0_[j + 4] = f2b(BB[1][j]);                      \
      t1_[j] = f2b(BB[2][j]); t1_[j + 4] = f2b(BB[3][j]);                      \
    }                                                                          \
    bf16x8 f0_ = __builtin_bit_cast(bf16x8, t0_);                              \
    bf16x8 f1_ = __builtin_bit_cast(bf16x8, t1_);                              \
    _Pragma("unroll")                                                          \
    for (int mt = 0; mt < MT_; ++mt) {                                         \
      acc[mt][0] = __builtin_amdgcn_mfma_f32_16x16x32_bf16(AS[mt], f0_,        \
                                                           acc[mt][0], 0,0,0); \
      acc[mt][1] = __builtin_amdgcn_mfma_f32_16x16x32_bf16(AS[mt], f1_,        \
                                                           acc[mt][1], 0,0,0); \
    }                                                                          \
    if (DO_A) {                                                                \
      _Pragma("unroll")                                                        \
      for (int mt = 0; mt < MT_; ++mt)                                         \
        AS[mt] = ldb8(apt + ((size_t)(mt * 256 + kbb +                         \
                                      (SGN) * ((T) + (P) + 2)) << 9));         \
    }                                                                          \
    if (DO_B) {                                                                \
      BB[0] = *reinterpret_cast<const f32x4*>(bpt0 + (SGN)*((T)+(P)+4)*32);    \
      BB[1] = *reinterpret_cast<const f32x4*>(bpt0 + (SGN)*((T)+(P)+4)*32 + 4);\
      BB[2] = *reinterpret_cast<const f32x4*>(bpt1 + (SGN)*((T)+(P)+4)*32);    \
      BB[3] = *reinterpret_cast<const f32x4*>(bpt1 + (SGN)*((T)+(P)+4)*32 + 4);\
    }                                                                          \
  }

#define KPROLOGUE(MT, SGN)                                                     \
  _Pragma("unroll")                                                            \
  for (int mt = 0; mt < (MT); ++mt)                                            \
    aS0[mt] = ldb8(apt + ((size_t)(mt * 256 + kbb) << 9));                     \
  bb0[0] = *reinterpret_cast<const f32x4*>(bpt0);                              \
  bb0[1] = *reinterpret_cast<const f32x4*>(bpt0 + 4);                          \
  bb0[2] = *reinterpret_cast<const f32x4*>(bpt1);                              \
  bb0[3] = *reinterpret_cast<const f32x4*>(bpt1 + 4);                          \
  _Pragma("unroll")                                                            \
  for (int mt = 0; mt < (MT); ++mt)                                            \
    aS1[mt] = ldb8(apt + ((size_t)(mt * 256 + kbb + (SGN)) << 9));             \
  bb1[0] = *reinterpret_cast<const f32x4*>(bpt0 + (SGN) * 32);                 \
  bb1[1] = *reinterpret_cast<const f32x4*>(bpt0 + (SGN) * 32 + 4);             \
  bb1[2] = *reinterpret_cast<const f32x4*>(bpt1 + (SGN) * 32);                 \
  bb1[3] = *reinterpret_cast<const f32x4*>(bpt1 + (SGN) * 32 + 4);             \
  bb2[0] = *reinterpret_cast<const f32x4*>(bpt0 + (SGN) * 64);                 \
  bb2[1] = *reinterpret_cast<const f32x4*>(bpt0 + (SGN) * 64 + 4);             \
  bb2[2] = *reinterpret_cast<const f32x4*>(bpt1 + (SGN) * 64);                 \
  bb2[3] = *reinterpret_cast<const f32x4*>(bpt1 + (SGN) * 64 + 4);             \
  bb3[0] = *reinterpret_cast<const f32x4*>(bpt0 + (SGN) * 96);                 \
  bb3[1] = *reinterpret_cast<const f32x4*>(bpt0 + (SGN) * 96 + 4);             \
  bb3[2] = *reinterpret_cast<const f32x4*>(bpt1 + (SGN) * 96);                 \
  bb3[3] = *reinterpret_cast<const f32x4*>(bpt1 + (SGN) * 96 + 4);

#define KMAIN(SGN)                                                             \
  for (int t = 0; t < 28; t += 4) {                                            \
    KPH(bb0, aS0, t, 0, 1, 1, SGN);                                            \
    KPH(bb1, aS1, t, 1, 1, 1, SGN);                                            \
    KPH(bb2, aS0, t, 2, 1, 1, SGN);                                            \
    KPH(bb3, aS1, t, 3, 1, 1, SGN);                                            \
  }                                                                            \
  KPH(bb0, aS0, 28, 0, 1, 0, SGN);                                             \
  KPH(bb1, aS1, 28, 1, 1, 0, SGN);                                             \
  KPH(bb2, aS0, 28, 2, 0, 0, SGN);                                             \
  KPH(bb3, aS1, 28, 3, 0, 0, SGN);

// K2: h^T = S^T @ adj (FORWARD stream). 32 adj rows/block, 8-wave K-split.
__global__ __launch_bounds__(512, 2) void k2_hidden(const float* __restrict__ ADJ,
                                                    const unsigned short* __restrict__ Stf,
                                                    const float* __restrict__ b1,
                                                    unsigned short* __restrict__ H)
{
  __shared__ float Ls[8 * 4096];            // 128 KB: per-wave partial C
  __shared__ unsigned short Hs[32 * 128];   // 8 KB staging for coalesced store
  const int tid = threadIdx.x;
  const int lane = tid & 63, w = tid >> 6;
  const int l15 = lane & 15, lg = lane >> 4;
  const int n0 = blockIdx.x * 32;
  const int kbg0 = w * 32;
  const int kbb = kbg0;                     // forward: start at panel start
  constexpr int MT_ = 8;

  const float* bpt0 = ADJ + (size_t)(n0 + l15) * NROW + kbb * 32 + lg * 8;
  const float* bpt1 = bpt0 + (size_t)16 * NROW;
  const unsigned short* apt = Stf + lane * 8;

  f32x4 acc[MT_][2];
#pragma unroll
  for (int m = 0; m < MT_; ++m) { acc[m][0] = f32x4{}; acc[m][1] = f32x4{}; }

  bf16x8 aS0[MT_], aS1[MT_];
  f32x4 bb0[4], bb1[4], bb2[4], bb3[4];
  KPROLOGUE(MT_, 1);
  KMAIN(1);

  // partials -> LDS: element e = c*32 + nl (c = hidden 0..127, nl = row 0..31)
#pragma unroll
  for (int mt = 0; mt < MT_; ++mt)
#pragma unroll
    for (int c2 = 0; c2 < 2; ++c2)
#pragma unroll
      for (int i = 0; i < 4; ++i)
        Ls[w * 4096 + (mt * 16 + lg * 4 + i) * 32 + c2 * 16 + l15] = acc[mt][c2][i];
  __syncthreads();

  // reduce 8 slabs: thread -> 8 elems (same c, nl0..nl0+7)
  {
    const int e0 = tid * 8;
    f32x4 s0 = {}, s1 = {};
#pragma unroll
    for (int ww = 0; ww < 8; ++ww) {
      s0 += *reinterpret_cast<const f32x4*>(&Ls[ww * 4096 + e0]);
      s1 += *reinterpret_cast<const f32x4*>(&Ls[ww * 4096 + e0 + 4]);
    }
    const int c = e0 >> 5;
    const int nl0 = e0 & 31;
    const float bias = b1[c];
    float v[8];
#pragma unroll
    for (int j = 0; j < 4; ++j) { v[j] = s0[j] + bias; v[j + 4] = s1[j] + bias; }
#pragma unroll
    for (int j = 0; j < 8; ++j) {
      float r = v[j] > 0.f ? v[j] : 0.f;
      Hs[(nl0 + j) * 128 + c] = f2b(r);
    }
  }
  __syncthreads();
  // coalesced store: thread -> row nl = tid>>4, cols (tid&15)*8..+7
  {
    const int nl = tid >> 4, cc = (tid & 15) * 8;
    u16x8 vv = *reinterpret_cast<const u16x8*>(&Hs[nl * 128 + cc]);
    *reinterpret_cast<u16x8*>(H + (size_t)(n0 + nl) * HID + cc) = vv;
  }
}

// K3: s2 = h @ W2 -> S2f B-fragment-linear (rounds 5-9 verbatim)
__global__ __launch_bounds__(256) void k3_s2(const unsigned short* __restrict__ H,
                                             const float* __restrict__ W2,
                                             unsigned short* __restrict__ S2f)
{
  __shared__ unsigned short W2t[64 * 136];
  const int tid = threadIdx.x;
  {
    const int n = tid >> 2;
    const int ks = (tid & 3) * 32;
    for (int j = 0; j < 32; ++j) {
      int k = ks + j;
      float v = (n < NCLS) ? W2[k * NCLS + n] : 0.f;
      W2t[n * 136 + k] = f2b(v);
    }
  }
  __syncthreads();
  const int lane = tid & 63, wave = tid >> 6;
  const int l15 = lane & 15, lg = lane >> 4;
  const int blk = blockIdx.x;
  const int m0 = blk * 64;
  const int rowm = m0 + wave * 16 + l15;
  f32x4 acc[4] = {};
#pragma unroll
  for (int kk = 0; kk < 4; ++kk) {
    bf16x8 af = *reinterpret_cast<const bf16x8*>(H + (size_t)rowm * HID + kk * 32 + lg * 8);
#pragma unroll
    for (int n = 0; n < 4; ++n) {
      bf16x8 bf = *reinterpret_cast<const bf16x8*>(&W2t[(n * 16 + l15) * 136 + kk * 32 + lg * 8]);
      acc[n] = __builtin_amdgcn_mfma_f32_16x16x32_bf16(af, bf, acc[n], 0, 0, 0);
    }
  }
  const int kb  = blk * 2 + (wave >> 1);
  const int lgc = ((wave & 1) << 1) + (lg >> 1);
  const int jb  = (lg & 1) * 4;
#pragma unroll
  for (int n = 0; n < 4; ++n) {
    u16x4 pk;
#pragma unroll
    for (int i = 0; i < 4; ++i) pk[i] = f2b(acc[n][i]);
    *reinterpret_cast<u16x4*>(S2f + (size_t)(n * 256 + kb) * 512 +
                              (l15 + 16 * lgc) * 8 + jb) = pk;
  }
}

// K4: logits^T = s2^T @ adj (+b2) -> log_softmax -> OUT. BACKWARD stream:
// consumes L3 in reverse-recency order of k2's forward pass.
__global__ __launch_bounds__(512, 2) void k4_out(const float* __restrict__ ADJ,
                                                 const unsigned short* __restrict__ S2f,
                                                 const float* __restrict__ b2,
                                                 float* __restrict__ OUT)
{
  __shared__ float Ls[8 * 2048];   // 64 KB
  __shared__ float Lg[32 * 64];    // 8 KB logits [row][class]
  const int tid = threadIdx.x;
  const int lane = tid & 63, w = tid >> 6;
  const int l15 = lane & 15, lg = lane >> 4;
  const int n0 = blockIdx.x * 32;
  const int kbg0 = w * 32;
  const int kbb = kbg0 + 31;                // backward: start at panel end
  constexpr int MT_ = 4;

  const float* bpt0 = ADJ + (size_t)(n0 + l15) * NROW + kbb * 32 + lg * 8;
  const float* bpt1 = bpt0 + (size_t)16 * NROW;
  const unsigned short* apt = S2f + lane * 8;

  f32x4 acc[MT_][2];
#pragma unroll
  for (int m = 0; m < MT_; ++m) { acc[m][0] = f32x4{}; acc[m][1] = f32x4{}; }

  bf16x8 aS0[MT_], aS1[MT_];
  f32x4 bb0[4], bb1[4], bb2[4], bb3[4];
  KPROLOGUE(MT_, -1);
  KMAIN(-1);

#pragma unroll
  for (int mt = 0; mt < MT_; ++mt)
#pragma unroll
    for (int c2 = 0; c2 < 2; ++c2)
#pragma unroll
      for (int i = 0; i < 4; ++i)
        Ls[w * 2048 + (mt * 16 + lg * 4 + i) * 32 + c2 * 16 + l15] = acc[mt][c2][i];
  __syncthreads();

  // reduce: thread -> 4 elems (same class c, rows nl0..nl0+3)
  {
    const int e0 = tid * 4;
    f32x4 s = {};
#pragma unroll
    for (int ww = 0; ww < 8; ++ww)
      s += *reinterpret_cast<const f32x4*>(&Ls[ww * 2048 + e0]);
    const int c = e0 >> 5;
    const int nl0 = e0 & 31;
    const float bias = (c < NCLS) ? b2[c] : 0.f;
#pragma unroll
    for (int j = 0; j < 4; ++j)
      Lg[(nl0 + j) * 64 + c] = s[j] + bias;
  }
  __syncthreads();

  // log_softmax: 32 rows x 16 threads
  {
    const int row = tid >> 4;
    const int sub = tid & 15;
    float vals[3];
    int nc = 0;
    float mx = -3.4e38f;
    for (int c = sub; c < NCLS; c += 16) {
      float v = Lg[row * 64 + c];
      vals[nc++] = v;
      mx = fmaxf(mx, v);
    }
#pragma unroll
    for (int d = 1; d < 16; d <<= 1) mx = fmaxf(mx, __shfl_xor(mx, d));
    float se = 0.f;
    for (int j = 0; j < nc; ++j) se += expf(vals[j] - mx);
#pragma unroll
    for (int d = 1; d < 16; d <<= 1) se += __shfl_xor(se, d);
    const float lse = mx + logf(se);
    int j = 0;
    for (int c = sub; c < NCLS; c += 16)
      OUT[(size_t)(n0 + row) * NCLS + c] = vals[j++] - lse;
  }
}

extern "C" void kernel_launch(void* const* d_in, const int* in_sizes, int n_in,
                              void* d_out, int out_size, void* d_ws, size_t ws_size,
                              hipStream_t stream)
{
  const float* x   = (const float*)d_in[0];
  const float* adj = (const float*)d_in[1];
  const float* W1  = (const float*)d_in[2];
  const float* b1  = (const float*)d_in[3];
  const float* W2  = (const float*)d_in[4];
  const float* b2  = (const float*)d_in[5];
  float* out = (float*)d_out;

  char* ws = (char*)d_ws;
  unsigned short* W1f = (unsigned short*)(ws);                          // 128KB
  unsigned short* Stf = (unsigned short*)(ws + 131072);                 // 2MB
  unsigned short* H   = (unsigned short*)(ws + 131072 + 2097152);       // 2MB
  unsigned short* S2f = (unsigned short*)(ws + 131072 + 2 * 2097152);   // 1MB

  hipLaunchKernelGGL(k0_w1f,     dim3(32),  dim3(256), 0, stream, W1, W1f);
  hipLaunchKernelGGL(k1_support, dim3(512), dim3(256), 0, stream, x, W1f, Stf);
  hipLaunchKernelGGL(k2_hidden,  dim3(256), dim3(512), 0, stream, adj, Stf, b1, H);
  hipLaunchKernelGGL(k3_s2,      dim3(128), dim3(256), 0, stream, H, W2, S2f);
  hipLaunchKernelGGL(k4_out,     dim3(256), dim3(512), 0, stream, adj, S2f, b2, out);
}